// Round 6
// baseline (145.661 us; speedup 1.0000x reference)
//
#include <hip/hip_runtime.h>
#include <math.h>

// Problem constants (reference: N=8, MA=24, DESIGN=26, RADIAL=15, SOFTENING=3, RM=5.0)
constexpr int MAC = 24;            // atoms per molecule
constexpr int DES = 26;            // sphere design points
constexpr int RAD = 15;            // radial points
constexpr int MS  = RAD * DES;     // 390 samples per atom
constexpr int MX  = MAC * MS;      // 9360 grid points per molecule
constexpr int PPG = 5;             // points per 32-lane group (5-way ILP)
constexpr int GPB = 6;             // groups per block -> 192 threads (3 waves)
constexpr int PPB = PPG * GPB;     // 30 points per block
constexpr int BPM = MX / PPB;      // 312 blocks per molecule (exact)
constexpr int REPS = 4;            // MEASUREMENT: internal repeats of the hot body

// xor-butterfly step within each 32-lane half (bit-mode ds_swizzle)
template <int M>
__device__ __forceinline__ float xorswz(float v) {
    return __int_as_float(__builtin_amdgcn_ds_swizzle(__float_as_int(v), (M << 10) | 0x1f));
}

// ---------------------------------------------------------------------------
// Precompute (gridded): tables into d_ws.
//   inv_dm [nmol][24][24], conc4 [390] = {r*sx, r*sy, r*sz, sw*w},
//   cpad [nmol][24] coords as float4, onev [REPS] = 1.0f (opaque rep scale)
// ---------------------------------------------------------------------------
__global__ __launch_bounds__(256) void becke_pre(
    const float* __restrict__ coords, const float* __restrict__ sphere,
    const float* __restrict__ sw, int nmol,
    float* __restrict__ inv_dm, float4* __restrict__ conc4,
    float4* __restrict__ cpad, float* __restrict__ onev)
{
    const int e = blockIdx.x * 256 + threadIdx.x;
    const int nidm = nmol * MAC * MAC;
    if (e < nidm) {
        int n = e / (MAC * MAC), r0 = e - n * MAC * MAC;
        int i = r0 / MAC, j = r0 - i * MAC;
        const float* cb = coords + n * MAC * 3;
        float dx = cb[i * 3 + 0] - cb[j * 3 + 0];
        float dy = cb[i * 3 + 1] - cb[j * 3 + 1];
        float dz = cb[i * 3 + 2] - cb[j * 3 + 2];
        float dd = sqrtf(dx * dx + dy * dy + dz * dz);
        inv_dm[e] = 1.0f / fmaxf(dd, 1e-12f);
        return;
    }
    const int e2 = e - nidm;
    if (e2 < MS) {
        int k = e2 / DES, d = e2 - k * DES;
        double i   = (double)k + 1.0;
        double z   = -cos(M_PI * (2.0 * i - 1.0) / (2.0 * (double)RAD));
        double omz = 1.0 - z;
        double dr  = 10.0 / (omz * omz);            // 2*RM, RM = 5.0
        double r   = 5.0 * (1.0 + z) / omz;
        double w1  = sqrt(1.0 - z * z) * dr * M_PI / (double)RAD;
        double w   = r * r * 4.0 * M_PI * w1;
        conc4[e2] = make_float4((float)(r * (double)sphere[d * 3 + 0]),
                                (float)(r * (double)sphere[d * 3 + 1]),
                                (float)(r * (double)sphere[d * 3 + 2]),
                                (float)((double)sw[d] * w));
        return;
    }
    const int e3 = e2 - MS;
    if (e3 < nmol * MAC) {
        cpad[e3] = make_float4(coords[e3 * 3 + 0], coords[e3 * 3 + 1],
                               coords[e3 * 3 + 2], 0.0f);
        return;
    }
    const int e4 = e3 - nmol * MAC;
    if (e4 < REPS) onev[e4] = 1.0f;   // opaque exact-identity scale
}

// ---------------------------------------------------------------------------
// Hot kernel (R5 structure) with REPS-x internal repeat for measurement.
// Each rep multiplies the distance vector by onev[rep]==1.0f (opaque to the
// compiler, exact in fp32), forcing full re-execution of the hot chain.
// Stores are idempotent (same address, same value).
// ---------------------------------------------------------------------------
__global__ __launch_bounds__(192) void becke_main(
    const float4* __restrict__ cpad,    // [nmol*24]
    const float*  __restrict__ inv_dm,  // [nmol*24*24]
    const float4* __restrict__ conc4,   // [390]
    const float*  __restrict__ onev,    // [REPS], all 1.0f
    float* __restrict__ og,             // [nmol, MX, 3]
    float* __restrict__ odv,            // [nmol, MX, 24, 3]
    float* __restrict__ ow)             // [nmol, MX]
{
    __shared__ float rxsh[GPB][PPG][32];   // [group][point][lane]

    const int tid = threadIdx.x;
    const int l   = tid & 31;
    const int grp = tid >> 5;
    const int b   = blockIdx.x;
    const int n   = b / BPM;
    const int bm  = b - n * BPM;
    const int s0  = bm * PPB + grp * PPG;
    const bool act = (l < MAC);
    const int  i   = act ? l : (MAC - 1);

    int ap[PPG], tp[PPG];
    #pragma unroll
    for (int p = 0; p < PPG; ++p) {
        int sp = s0 + p;
        ap[p] = sp / MS;
        tp[p] = sp - ap[p] * MS;
    }

    const float4 ci = cpad[n * MAC + i];

    float gx[PPG], gy[PPG], gz[PPG], wt[PPG];
    #pragma unroll
    for (int p = 0; p < PPG; ++p) {
        float4 cc = conc4[tp[p]];
        float4 ca = cpad[n * MAC + ap[p]];
        gx[p] = ca.x + cc.x;
        gy[p] = ca.y + cc.y;
        gz[p] = ca.z + cc.z;
        wt[p] = cc.w;
    }

    // lane's inv_dm row: 6 x dwordx4 (loop-invariant, stays out of rep loop)
    float inv[MAC];
    {
        const float* irow = inv_dm + (n * MAC + i) * MAC;
        #pragma unroll
        for (int q = 0; q < MAC / 4; ++q) {
            float4 v = *reinterpret_cast<const float4*>(irow + q * 4);
            inv[q * 4 + 0] = v.x; inv[q * 4 + 1] = v.y;
            inv[q * 4 + 2] = v.z; inv[q * 4 + 3] = v.w;
        }
    }

    const size_t sgb = (size_t)n * MX + s0;

    for (int rep = 0; rep < REPS; ++rep) {
        const float fs = onev[rep];   // 1.0f, opaque -> body re-executes

        float rx[PPG];
        #pragma unroll
        for (int p = 0; p < PPG; ++p) {
            float dx = (gx[p] - ci.x) * fs;
            float dy = (gy[p] - ci.y) * fs;
            float dz = (gz[p] - ci.z) * fs;
            if (act) {
                float* dvp = odv + ((sgb + p) * MAC + i) * 3;
                dvp[0] = dx; dvp[1] = dy; dvp[2] = dz;
            }
            rx[p] = sqrtf(dx * dx + dy * dy + dz * dz);
            rxsh[grp][p][l] = rx[p];     // wave-synchronous exchange
        }
        __builtin_amdgcn_wave_barrier();

        float prod[PPG] = {1.0f, 1.0f, 1.0f, 1.0f, 1.0f};
        #pragma unroll
        for (int p = 0; p < PPG; ++p) {
            const float4* rxv = reinterpret_cast<const float4*>(&rxsh[grp][p][0]);
            const float rxi = rx[p];
            #pragma unroll
            for (int q = 0; q < MAC / 4; ++q) {
                float4 r4 = rxv[q];                 // broadcast read
                #pragma unroll
                for (int u = 0; u < 4; ++u) {
                    float rj = (u == 0) ? r4.x : (u == 1) ? r4.y : (u == 2) ? r4.z : r4.w;
                    float mu = (rxi - rj) * inv[q * 4 + u];
                    mu *= fmaf(mu * mu, -0.5f, 1.5f);   // softening 1
                    mu *= fmaf(mu * mu, -0.5f, 1.5f);   // softening 2
                    prod[p] *= fmaf(mu, -0.5f, 0.5f);   // s = 0.5*(1-mu)
                }
            }
        }

        #pragma unroll
        for (int p = 0; p < PPG; ++p) {
            float cell = act ? (prod[p] + prod[p]) : 0.0f;
            float sum = cell;
            sum += xorswz<1>(sum);
            sum += xorswz<2>(sum);
            sum += xorswz<4>(sum);
            sum += xorswz<8>(sum);
            sum += xorswz<16>(sum);
            if (l == ap[p])
                ow[sgb + p] = cell * __builtin_amdgcn_rcpf(sum) * wt[p];
        }

        if (l >= MAC && l < MAC + PPG) {   // pad lanes store grid points
            int p = l - MAC;
            float* gp = og + (sgb + p) * 3;
            gp[0] = gx[p] * fs + ci.x * (1.0f - fs) ;  // == gx[p] when fs==1
            gp[1] = gy[p] * fs + ci.y * (1.0f - fs);
            gp[2] = gz[p] * fs + ci.z * (1.0f - fs);
        }
    }
}

extern "C" void kernel_launch(void* const* d_in, const int* in_sizes, int n_in,
                              void* d_out, int out_size, void* d_ws, size_t ws_size,
                              hipStream_t stream) {
    // inputs: [0]=labels (unused), [1]=coords f32 [N,24,3],
    //         [2]=sphere f32 [26,3], [3]=sphere_weights f32 [26]
    const float* coords = (const float*)d_in[1];
    const float* sphere = (const float*)d_in[2];
    const float* sw     = (const float*)d_in[3];

    const int nmol = in_sizes[1] / (MAC * 3);   // 8

    float*  ws     = (float*)d_ws;
    float*  inv_dm = ws;                                           // nmol*576 floats
    float4* conc4  = (float4*)(inv_dm + (size_t)nmol * MAC * MAC); // 390 float4
    float4* cpad   = conc4 + MS;                                   // nmol*24 float4
    float*  onev   = (float*)(cpad + nmol * MAC);                  // REPS floats

    float* o     = (float*)d_out;
    float* ogrid = o;                                        // [N, MX, 3]
    float* odv   = ogrid + (size_t)nmol * MX * 3;            // [N, MX, 24, 3]
    float* owt   = odv + (size_t)nmol * MX * MAC * 3;        // [N, MX]

    const int pre_elems  = nmol * MAC * MAC + MS + nmol * MAC + REPS;
    const int pre_blocks = (pre_elems + 255) / 256;
    becke_pre<<<dim3(pre_blocks), dim3(256), 0, stream>>>(
        coords, sphere, sw, nmol, inv_dm, conc4, cpad, onev);

    becke_main<<<dim3(nmol * BPM), dim3(192), 0, stream>>>(
        cpad, inv_dm, conc4, onev, ogrid, odv, owt);
}

// Round 7
// 83.020 us; speedup vs baseline: 1.7545x; 1.7545x over previous
//
#include <hip/hip_runtime.h>
#include <math.h>

// Problem constants (reference: N=8, MA=24, DESIGN=26, RADIAL=15, SOFTENING=3, RM=5.0)
constexpr int MAC = 24;            // atoms per molecule
constexpr int DES = 26;            // sphere design points
constexpr int RAD = 15;            // radial points
constexpr int MS  = RAD * DES;     // 390 samples per atom
constexpr int MX  = MAC * MS;      // 9360 grid points per molecule
constexpr int PPG = 3;             // points per 32-lane group (3-way ILP)
constexpr int GPB = 10;            // groups per block -> 320 threads (5 waves)
constexpr int PPB = PPG * GPB;     // 30 points per block
constexpr int BPM = MX / PPB;      // 312 blocks per molecule (exact)
constexpr int BPA = MS / PPB;      // 13 blocks per atom (EXACT: 390 = 13*30)
                                   // -> parent atom is block-uniform!

// xor-butterfly step within each 32-lane half (bit-mode ds_swizzle)
template <int M>
__device__ __forceinline__ float xorswz(float v) {
    return __int_as_float(__builtin_amdgcn_ds_swizzle(__float_as_int(v), (M << 10) | 0x1f));
}

// ---------------------------------------------------------------------------
// Precompute (gridded): tables into d_ws.
//   inv_dm [nmol][24][24], conc4 [390] = {r*sx, r*sy, r*sz, sw*w},
//   cpad   [nmol][24]     = coords padded to float4
// ---------------------------------------------------------------------------
__global__ __launch_bounds__(256) void becke_pre(
    const float* __restrict__ coords, const float* __restrict__ sphere,
    const float* __restrict__ sw, int nmol,
    float* __restrict__ inv_dm, float4* __restrict__ conc4, float4* __restrict__ cpad)
{
    const int e = blockIdx.x * 256 + threadIdx.x;
    const int nidm = nmol * MAC * MAC;
    if (e < nidm) {
        int n = e / (MAC * MAC), r0 = e - n * MAC * MAC;
        int i = r0 / MAC, j = r0 - i * MAC;
        const float* cb = coords + n * MAC * 3;
        float dx = cb[i * 3 + 0] - cb[j * 3 + 0];
        float dy = cb[i * 3 + 1] - cb[j * 3 + 1];
        float dz = cb[i * 3 + 2] - cb[j * 3 + 2];
        float dd = sqrtf(dx * dx + dy * dy + dz * dz);
        inv_dm[e] = 1.0f / fmaxf(dd, 1e-12f);
        return;
    }
    const int e2 = e - nidm;
    if (e2 < MS) {
        int k = e2 / DES, d = e2 - k * DES;
        double i   = (double)k + 1.0;
        double z   = -cos(M_PI * (2.0 * i - 1.0) / (2.0 * (double)RAD));
        double omz = 1.0 - z;
        double dr  = 10.0 / (omz * omz);            // 2*RM, RM = 5.0
        double r   = 5.0 * (1.0 + z) / omz;
        double w1  = sqrt(1.0 - z * z) * dr * M_PI / (double)RAD;
        double w   = r * r * 4.0 * M_PI * w1;
        conc4[e2] = make_float4((float)(r * (double)sphere[d * 3 + 0]),
                                (float)(r * (double)sphere[d * 3 + 1]),
                                (float)(r * (double)sphere[d * 3 + 2]),
                                (float)((double)sw[d] * w));
        return;
    }
    const int e3 = e2 - MS;
    if (e3 < nmol * MAC) {
        cpad[e3] = make_float4(coords[e3 * 3 + 0], coords[e3 * 3 + 1],
                               coords[e3 * 3 + 2], 0.0f);
    }
}

// ---------------------------------------------------------------------------
// Hot kernel: 32 lanes per point-group, 3 points/group, 320 thr/block.
// Parent atom block-uniform (390 = 13*30) -> scalar index math.
// rx exchanged via wave-synchronous LDS; no __syncthreads.
// ---------------------------------------------------------------------------
__global__ __launch_bounds__(320) void becke_main(
    const float4* __restrict__ cpad,    // [nmol*24]
    const float*  __restrict__ inv_dm,  // [nmol*24*24]
    const float4* __restrict__ conc4,   // [390]
    float* __restrict__ og,             // [nmol, MX, 3]
    float* __restrict__ odv,            // [nmol, MX, 24, 3]
    float* __restrict__ ow)             // [nmol, MX]
{
    __shared__ float rxsh[GPB][PPG][32];   // 3.84 KB

    const int tid = threadIdx.x;
    const int l   = tid & 31;
    const int grp = tid >> 5;
    const int b   = blockIdx.x;
    const int n   = b / BPM;                       // molecule (uniform)
    const int bm  = b - n * BPM;
    const int a   = bm / BPA;                      // parent atom (block-uniform!)
    const int t0  = (bm - a * BPA) * PPB + grp * PPG;  // first sample of group
    const bool act = (l < MAC);
    const int  i   = act ? l : (MAC - 1);

    const float4 ci = cpad[n * MAC + i];           // lane's atom
    const float4 ca = cpad[n * MAC + a];           // parent atom (scalar)

    float gx[PPG], gy[PPG], gz[PPG], wt[PPG], rx[PPG];
    float dxv[PPG], dyv[PPG], dzv[PPG];
    #pragma unroll
    for (int p = 0; p < PPG; ++p) {
        float4 cc = conc4[t0 + p];
        gx[p] = ca.x + cc.x;
        gy[p] = ca.y + cc.y;
        gz[p] = ca.z + cc.z;
        wt[p] = cc.w;
        dxv[p] = gx[p] - ci.x;
        dyv[p] = gy[p] - ci.y;
        dzv[p] = gz[p] - ci.z;
        // raw v_sqrt_f32 (~1 ulp) — threshold slack is ~2%, plenty
        rx[p] = __builtin_amdgcn_sqrtf(dxv[p] * dxv[p] + dyv[p] * dyv[p] + dzv[p] * dzv[p]);
        rxsh[grp][p][l] = rx[p];     // wave-synchronous exchange (same wave)
    }
    __builtin_amdgcn_wave_barrier();  // compiler ordering; DS pipe in-order per wave

    const size_t sgb = (size_t)n * MX + a * MS + t0;

    // dv stores: one exec-toggle, immediate-offset stores (p stride = 288 B)
    if (act) {
        float* dvp = odv + (sgb * MAC + i) * 3;
        #pragma unroll
        for (int p = 0; p < PPG; ++p) {
            dvp[p * MAC * 3 + 0] = dxv[p];
            dvp[p * MAC * 3 + 1] = dyv[p];
            dvp[p * MAC * 3 + 2] = dzv[p];
        }
    }

    // lane's inv_dm row: 6 x dwordx4 (2.3 KB table, L1-hot)
    float inv[MAC];
    {
        const float* irow = inv_dm + (n * MAC + i) * MAC;
        #pragma unroll
        for (int q = 0; q < MAC / 4; ++q) {
            float4 v = *reinterpret_cast<const float4*>(irow + q * 4);
            inv[q * 4 + 0] = v.x; inv[q * 4 + 1] = v.y;
            inv[q * 4 + 2] = v.z; inv[q * 4 + 3] = v.w;
        }
    }

    // Becke row products (diagonal included: s(0)=0.5 exactly, undone by *2)
    float prod[PPG] = {1.0f, 1.0f, 1.0f};
    #pragma unroll
    for (int p = 0; p < PPG; ++p) {
        const float4* rxv = reinterpret_cast<const float4*>(&rxsh[grp][p][0]);
        const float rxi = rx[p];
        #pragma unroll
        for (int q = 0; q < MAC / 4; ++q) {
            float4 r4 = rxv[q];                 // broadcast read, conflict-free
            #pragma unroll
            for (int u = 0; u < 4; ++u) {
                float rj = (u == 0) ? r4.x : (u == 1) ? r4.y : (u == 2) ? r4.z : r4.w;
                float mu = (rxi - rj) * inv[q * 4 + u];
                mu *= fmaf(mu * mu, -0.5f, 1.5f);   // softening pass 1
                mu *= fmaf(mu * mu, -0.5f, 1.5f);   // softening pass 2
                prod[p] *= fmaf(mu, -0.5f, 0.5f);   // s = 0.5*(1-mu)
            }
        }
    }

    #pragma unroll
    for (int p = 0; p < PPG; ++p) {
        float cell = act ? (prod[p] + prod[p]) : 0.0f;
        float sum = cell;
        sum += xorswz<1>(sum);
        sum += xorswz<2>(sum);
        sum += xorswz<4>(sum);
        sum += xorswz<8>(sum);
        sum += xorswz<16>(sum);
        if (l == a)   // uniform lane: lane a's prod IS cell_a; rcp ok (2% slack)
            ow[sgb + p] = cell * __builtin_amdgcn_rcpf(sum) * wt[p];
    }

    if (l >= MAC && l < MAC + PPG) {   // pad lanes 24..26 store grid points
        int p = l - MAC;
        float* gp = og + (sgb + p) * 3;
        gp[0] = gx[p]; gp[1] = gy[p]; gp[2] = gz[p];
    }
}

extern "C" void kernel_launch(void* const* d_in, const int* in_sizes, int n_in,
                              void* d_out, int out_size, void* d_ws, size_t ws_size,
                              hipStream_t stream) {
    // inputs: [0]=labels (unused), [1]=coords f32 [N,24,3],
    //         [2]=sphere f32 [26,3], [3]=sphere_weights f32 [26]
    const float* coords = (const float*)d_in[1];
    const float* sphere = (const float*)d_in[2];
    const float* sw     = (const float*)d_in[3];

    const int nmol = in_sizes[1] / (MAC * 3);   // 8

    float*  ws     = (float*)d_ws;
    float*  inv_dm = ws;                                           // nmol*576 floats
    float4* conc4  = (float4*)(inv_dm + (size_t)nmol * MAC * MAC); // 390 float4
    float4* cpad   = conc4 + MS;                                   // nmol*24 float4

    float* o     = (float*)d_out;
    float* ogrid = o;                                        // [N, MX, 3]
    float* odv   = ogrid + (size_t)nmol * MX * 3;            // [N, MX, 24, 3]
    float* owt   = odv + (size_t)nmol * MX * MAC * 3;        // [N, MX]

    const int pre_elems  = nmol * MAC * MAC + MS + nmol * MAC;
    const int pre_blocks = (pre_elems + 255) / 256;
    becke_pre<<<dim3(pre_blocks), dim3(256), 0, stream>>>(
        coords, sphere, sw, nmol, inv_dm, conc4, cpad);

    becke_main<<<dim3(nmol * BPM), dim3(320), 0, stream>>>(
        cpad, inv_dm, conc4, ogrid, odv, owt);
}